// Round 15
// baseline (2614.756 us; speedup 1.0000x reference)
//
#include <hip/hip_runtime.h>

// Round 15: round 14 (green) with ONE change: amdgpu_waves_per_eu(3,3).
// Round 14's compiler chose 84 VGPRs (targeting 6 waves/SIMD) although LDS
// caps us at 12 waves = 3/SIMD -- half the RF unused, loads near-serial
// (round 10/11 proved this mechanism: 84->128 VGPR alone was -15%).
// Pinning waves/EU to exactly 3 lets regalloc use ~170 VGPRs for deep
// load pipelining. Everything else byte-identical to round 14.

typedef __attribute__((ext_vector_type(8))) short bf16x8;
typedef __attribute__((ext_vector_type(4))) float f32x4;

#define OFF_Q 0          // Q [176][64] bf16 stride 128 swizzled; Wproj[256][64]@128 overlays 0..32768
#define OFF_K 22528      // K [176][64] stride 128 swizzled; avT [64][176]@352 PLAIN overlays exactly
#define OFF_V 45056      // Vt [64][176]@352 PLAIN; act [176][64]@128 swizzled overlays
#define OFF_T 67584      // P_tmp: per wave 1152B = [16][36 bf16] stride 72 (12 waves)
#define SMEM_BYTES 81408

__device__ __forceinline__ unsigned short f2bf(float f) {
  unsigned int u = __float_as_uint(f);
  u += 0x7FFFu + ((u >> 16) & 1u);
  return (unsigned short)(u >> 16);
}
__device__ __forceinline__ float bf2f(unsigned short v) {
  return __uint_as_float(((unsigned int)v) << 16);
}
__device__ __forceinline__ f32x4 mfma16(bf16x8 a, bf16x8 b, f32x4 c) {
  return __builtin_amdgcn_mfma_f32_16x16x32_bf16(a, b, c, 0, 0, 0);
}
__device__ __forceinline__ bf16x8 cvt8(float4 a, float4 b) {
  bf16x8 v;
  v[0] = (short)f2bf(a.x); v[1] = (short)f2bf(a.y);
  v[2] = (short)f2bf(a.z); v[3] = (short)f2bf(a.w);
  v[4] = (short)f2bf(b.x); v[5] = (short)f2bf(b.y);
  v[6] = (short)f2bf(b.z); v[7] = (short)f2bf(b.w);
  return v;
}
// swizzled (stride must be multiple of 128)
__device__ __forceinline__ bf16x8 ld8s(const char* sm, int base, int stride, int row, int colbyte) {
  return *(const bf16x8*)(sm + base + row * stride + (colbyte ^ ((row & 7) << 4)));
}
__device__ __forceinline__ void st2s(char* sm, int base, int stride, int row, int col, unsigned short v) {
  *(unsigned short*)(sm + base + row * stride + ((col * 2) ^ ((row & 7) << 4))) = v;
}
// plain (any stride)
__device__ __forceinline__ bf16x8 ld8p(const char* sm, int base, int stride, int row, int colbyte) {
  return *(const bf16x8*)(sm + base + row * stride + colbyte);
}
__device__ __forceinline__ void st2p(char* sm, int base, int stride, int row, int col, unsigned short v) {
  *(unsigned short*)(sm + base + row * stride + col * 2) = v;
}
__device__ __forceinline__ float ld2p(const char* sm, int base, int stride, int row, int col) {
  return bf2f(*(const unsigned short*)(sm + base + row * stride + col * 2));
}

__global__ __launch_bounds__(768)
__attribute__((amdgpu_waves_per_eu(3, 3)))
void attn_kernel(
    const float* __restrict__ x, const float* __restrict__ qkv_w,
    const float* __restrict__ proj_w, const float* __restrict__ proj_b,
    const float* __restrict__ dwc_w, const float* __restrict__ dwc_b,
    const float* __restrict__ an, const float* __restrict__ ah,
    const float* __restrict__ aw, const float* __restrict__ na,
    const float* __restrict__ ha, const float* __restrict__ wa,
    float* __restrict__ out)
{
  __shared__ __align__(16) char sm[SMEM_BYTES];
  const int b = blockIdx.x;
  const int tid = threadIdx.x;
  const int wave = tid >> 6;        // 0..11; mt = wave; wave 11 idle in compute
  const int lane = tid & 63;
  const int l15 = lane & 15;
  const int l4 = lane >> 4;
  const int mt = wave;
  const float* xb = x + (size_t)b * 169 * 256;
  const f32x4 z = {0.f, 0.f, 0.f, 0.f};

  // one-time LDS zero: stray pad bytes must never decode to Inf/NaN
  {
    int* p = (int*)sm;
    for (int i = tid; i < SMEM_BYTES / 4; i += 768) p[i] = 0;
  }

  // fused S-phase (in-reg softmax) + PV via per-wave P_tmp. One m-tile/wave.
  auto fused = [&](int sBase, int pvBase, int which, int h, f32x4 (&o)[4]) {
#pragma unroll
    for (int dt = 0; dt < 4; ++dt) o[dt] = z;
    if (mt >= 11) return;
    const int arow = mt * 16 + l15;
    const int rbase = mt * 16 + l4 * 4;
    bf16x8 a0 = ld8s(sm, OFF_Q, 128, arow, l4 * 16);
    bf16x8 a1 = ld8s(sm, OFF_Q, 128, arow, 64 + l4 * 16);
    f32x4 s[11];
#pragma unroll
    for (int nt = 0; nt < 11; ++nt) {
      const int brow = nt * 16 + l15;
      bf16x8 b0 = ld8s(sm, sBase, 128, brow, l4 * 16);
      bf16x8 b1 = ld8s(sm, sBase, 128, brow, 64 + l4 * 16);
      f32x4 c = z;
      c = mfma16(a0, b0, c);
      c = mfma16(a1, b1, c);
      s[nt] = c;
    }
    // bias + mask
#pragma unroll
    for (int nt = 0; nt < 11; ++nt) {
      const int cc = nt * 16 + l15;
      const int ccl = cc > 168 ? 168 : cc;
      const int yc = (ccl * 79) >> 10;
      const int xc = ccl - yc * 13;
#pragma unroll
      for (int r = 0; r < 4; ++r) {
        const int rr = rbase + r;
        const int rrl = rr > 168 ? 168 : rr;
        float bias;
        if (which == 0) {
          bias = an[h * 28561 + rrl * 169 + ccl]
               + ah[(h * 169 + rrl) * 13 + yc]
               + aw[(h * 169 + rrl) * 13 + xc];
        } else {
          const int yn = (rrl * 79) >> 10;
          const int xn = rrl - yn * 13;
          bias = na[h * 28561 + ccl * 169 + rrl]
               + ha[(h * 13 + yn) * 169 + ccl]
               + wa[(h * 13 + xn) * 169 + ccl];
        }
        const float v = s[nt][r] * 0.125f + bias;
        s[nt][r] = (cc > 168) ? -3.0e38f : v;
      }
    }
    // in-register softmax
#pragma unroll
    for (int r = 0; r < 4; ++r) {
      float m = s[0][r];
#pragma unroll
      for (int nt = 1; nt < 11; ++nt) m = fmaxf(m, s[nt][r]);
      m = fmaxf(m, __shfl_xor(m, 1));
      m = fmaxf(m, __shfl_xor(m, 2));
      m = fmaxf(m, __shfl_xor(m, 4));
      m = fmaxf(m, __shfl_xor(m, 8));
      float sum = 0.f;
#pragma unroll
      for (int nt = 0; nt < 11; ++nt) { const float e = __expf(s[nt][r] - m); s[nt][r] = e; sum += e; }
      sum += __shfl_xor(sum, 1);
      sum += __shfl_xor(sum, 2);
      sum += __shfl_xor(sum, 4);
      sum += __shfl_xor(sum, 8);
      const float inv = 1.f / sum;
#pragma unroll
      for (int nt = 0; nt < 11; ++nt) s[nt][r] *= inv;
    }
    // PV: per 32-wide chunk pair, round-trip through per-wave P_tmp
    const int tb = OFF_T + wave * 1152;
#pragma unroll
    for (int np = 0; np < 6; ++np) {
      const int nt1 = 2 * np + 1;
#pragma unroll
      for (int r = 0; r < 4; ++r) {
        char* prow = sm + tb + (l4 * 4 + r) * 72;
        *(unsigned short*)(prow + l15 * 2) = f2bf(s[2 * np][r]);
        *(unsigned short*)(prow + 32 + l15 * 2) =
            (nt1 < 11) ? f2bf(s[nt1][r]) : (unsigned short)0;
      }
      bf16x8 af = *(const bf16x8*)(sm + tb + l15 * 72 + l4 * 16);
#pragma unroll
      for (int dt = 0; dt < 4; ++dt) {
        bf16x8 bv = ld8p(sm, pvBase, 352, dt * 16 + l15, np * 64 + l4 * 16);
        o[dt] = mfma16(af, bv, o[dt]);
      }
    }
  };

  for (int h = 0; h < 4; ++h) {
    __syncthreads();   // previous head fully consumed (and initial zero done)

    // ---- QKV: [176 x 192] = x[b] @ w_head^T, direct-global frags ----
    if (mt < 11) {
      f32x4 acc[12];
#pragma unroll
      for (int i = 0; i < 12; ++i) acc[i] = z;
      const int arow = mt * 16 + l15;
      const int gr = arow < 169 ? arow : 168;

      for (int ks = 0; ks < 8; ++ks) {
        const float* p0 = xb + gr * 256 + ks * 32 + l4 * 8;
        bf16x8 af = cvt8(*(const float4*)p0, *(const float4*)(p0 + 4));
#pragma unroll
        for (int nt = 0; nt < 12; ++nt) {
          const int wrow = nt * 16 + l15;
          const int grow = ((wrow >> 6) << 8) + h * 64 + (wrow & 63);
          const float* wp = qkv_w + grow * 256 + ks * 32 + l4 * 8;
          bf16x8 bw = cvt8(*(const float4*)wp, *(const float4*)(wp + 4));
          acc[nt] = mfma16(af, bw, acc[nt]);
        }
      }
      // write Q,K row-major (stride 128, swz); V transposed [d][n] (stride 352, plain)
#pragma unroll
      for (int nt = 0; nt < 12; ++nt) {
        const int mat = nt >> 2;
        const int d = (nt & 3) * 16 + l15;
#pragma unroll
        for (int r = 0; r < 4; ++r) {
          const int n = mt * 16 + l4 * 4 + r;
          const unsigned short u = f2bf(acc[nt][r]);
          if (mat == 0)      st2s(sm, OFF_Q, 128, n, d, u);
          else if (mat == 1) st2s(sm, OFF_K, 128, n, d, u);
          else               st2p(sm, OFF_V, 352, d, n, u);
        }
      }
    }
    __syncthreads();

    // ---- S1 + P1V fused (B=K, PV-B=Vt) -> agent_v rows in regs ----
    f32x4 o1[4];
    fused(OFF_K, OFF_V, 0, h, o1);
    __syncthreads();                 // all S1 reads of K done
    // write avT [d][a] over K region (stride 352, plain)
    if (mt < 11) {
#pragma unroll
      for (int dt = 0; dt < 4; ++dt)
#pragma unroll
        for (int r = 0; r < 4; ++r)
          st2p(sm, OFF_K, 352, dt * 16 + l15, mt * 16 + l4 * 4 + r, f2bf(o1[dt][r]));
    }
    __syncthreads();

    // ---- S2 + P2A fused (B=Q, PV-B=avT) + dwconv epilogue (reads Vt) ----
    f32x4 o2[4];
    fused(OFF_Q, OFF_K, 1, h, o2);
    if (mt < 11) {
#pragma unroll
      for (int dt = 0; dt < 4; ++dt) {
        const int d = dt * 16 + l15;
        const int c = h * 64 + d;
        const float bc = dwc_b[c];
#pragma unroll
        for (int r = 0; r < 4; ++r) {
          const int n = mt * 16 + l4 * 4 + r;
          const int nl = n > 168 ? 168 : n;
          const int y = (nl * 79) >> 10;
          const int xx = nl - y * 13;
          float dw = bc;
#pragma unroll
          for (int ky = 0; ky < 3; ++ky) {
            const int yy = y + ky - 1;
            if ((unsigned)yy >= 13u) continue;
#pragma unroll
            for (int kx = 0; kx < 3; ++kx) {
              const int x2 = xx + kx - 1;
              if ((unsigned)x2 >= 13u) continue;
              dw += dwc_w[c * 9 + ky * 3 + kx] * ld2p(sm, OFF_V, 352, d, yy * 13 + x2);
            }
          }
          o2[dt][r] += dw;           // act value in regs
        }
      }
    }
    __syncthreads();                 // all dwconv reads of Vt done

    // ---- write act [n][d] over Vt region (stride 128, swz) + stage Wproj ----
    if (mt < 11) {
#pragma unroll
      for (int dt = 0; dt < 4; ++dt) {
        const int d = dt * 16 + l15;
#pragma unroll
        for (int r = 0; r < 4; ++r)
          st2s(sm, OFF_V, 128, mt * 16 + l4 * 4 + r, d, f2bf(o2[dt][r]));
      }
    }
    for (int idx = tid; idx < 2048; idx += 768) {
      const int j = idx >> 3;          // 0..255
      const int c8 = idx & 7;
      const float* src = proj_w + j * 256 + h * 64 + c8 * 8;
      float4 f0 = *(const float4*)(src);
      float4 f1 = *(const float4*)(src + 4);
      *(bf16x8*)(sm + OFF_Q + j * 128 + ((c8 * 16) ^ ((j & 7) << 4))) = cvt8(f0, f1);
    }
    __syncthreads();

    // ---- proj partial MFMA: out (+)= act @ Wproj^T (K=64), fp32 RMW ----
    if (mt < 11) {
      const int arow = mt * 16 + l15;
      bf16x8 af0 = ld8s(sm, OFF_V, 128, arow, l4 * 16);
      bf16x8 af1 = ld8s(sm, OFF_V, 128, arow, 64 + l4 * 16);
#pragma unroll
      for (int nt = 0; nt < 16; ++nt) {
        const int brow = nt * 16 + l15;
        bf16x8 bf0 = ld8s(sm, OFF_Q, 128, brow, l4 * 16);
        bf16x8 bf1 = ld8s(sm, OFF_Q, 128, brow, 64 + l4 * 16);
        f32x4 c = z;
        c = mfma16(af0, bf0, c);
        c = mfma16(af1, bf1, c);
        const int col = nt * 16 + l15;
#pragma unroll
        for (int r = 0; r < 4; ++r) {
          const int n = mt * 16 + l4 * 4 + r;
          if (n < 169) {
            float* p = out + ((size_t)b * 169 + n) * 256 + col;
            if (h == 0)      *p = c[r] + proj_b[col];
            else if (h == 3) __builtin_nontemporal_store(*p + c[r], p);
            else             *p += c[r];
          }
        }
      }
    }
    // next head's loop-top barrier protects Q/K/V regions
  }
}

extern "C" void kernel_launch(void* const* d_in, const int* in_sizes, int n_in,
                              void* d_out, int out_size, void* d_ws, size_t ws_size,
                              hipStream_t stream) {
  const float* x      = (const float*)d_in[0];
  const float* qkv_w  = (const float*)d_in[1];
  const float* proj_w = (const float*)d_in[2];
  const float* proj_b = (const float*)d_in[3];
  const float* dwc_w  = (const float*)d_in[4];
  const float* dwc_b  = (const float*)d_in[5];
  const float* an     = (const float*)d_in[6];
  const float* na     = (const float*)d_in[7];
  const float* ah     = (const float*)d_in[8];
  const float* aw     = (const float*)d_in[9];
  const float* ha     = (const float*)d_in[10];
  const float* wa     = (const float*)d_in[11];

  attn_kernel<<<1024, 768, 0, stream>>>(
      x, qkv_w, proj_w, proj_b, dwc_w, dwc_b,
      an, ah, aw, na, ha, wa, (float*)d_out);
}

// Round 16
// 2290.726 us; speedup vs baseline: 1.1415x; 1.1415x over previous
//
#include <hip/hip_runtime.h>

// Round 16: round 15 (green) with ONE conceptual change: each block processes
// TWO batches (b, b+512) with per-instruction interleaving. Grid 512, LDS
// 162,816B (2x per-b regions + 24 P_tmp slots). Forces 2 independent chains
// per wave (compiler must use >84 VGPRs: s[2][11] alone is 88) and makes
// qkv_w frags / bias gathers / Wproj staging SHARED (loaded once, used for
// both b). Numerics, swizzle rules, barriers, RMW epilogue unchanged.

typedef __attribute__((ext_vector_type(8))) short bf16x8;
typedef __attribute__((ext_vector_type(4))) float f32x4;

#define BSTR  67584      // per-b region: Q[0,22528) K/avT[22528,45056) V/act[45056,67584)
#define OFF_Q 0
#define OFF_K 22528
#define OFF_V 45056
#define OFF_T 135168     // P_tmp: per (wave,bb) 1152B = [16][36 bf16] stride 72
#define SMEM_BYTES 162816

__device__ __forceinline__ unsigned short f2bf(float f) {
  unsigned int u = __float_as_uint(f);
  u += 0x7FFFu + ((u >> 16) & 1u);
  return (unsigned short)(u >> 16);
}
__device__ __forceinline__ float bf2f(unsigned short v) {
  return __uint_as_float(((unsigned int)v) << 16);
}
__device__ __forceinline__ f32x4 mfma16(bf16x8 a, bf16x8 b, f32x4 c) {
  return __builtin_amdgcn_mfma_f32_16x16x32_bf16(a, b, c, 0, 0, 0);
}
__device__ __forceinline__ bf16x8 cvt8(float4 a, float4 b) {
  bf16x8 v;
  v[0] = (short)f2bf(a.x); v[1] = (short)f2bf(a.y);
  v[2] = (short)f2bf(a.z); v[3] = (short)f2bf(a.w);
  v[4] = (short)f2bf(b.x); v[5] = (short)f2bf(b.y);
  v[6] = (short)f2bf(b.z); v[7] = (short)f2bf(b.w);
  return v;
}
// swizzled (stride multiple of 128; base multiple of 128)
__device__ __forceinline__ bf16x8 ld8s(const char* sm, int base, int stride, int row, int colbyte) {
  return *(const bf16x8*)(sm + base + row * stride + (colbyte ^ ((row & 7) << 4)));
}
__device__ __forceinline__ void st2s(char* sm, int base, int stride, int row, int col, unsigned short v) {
  *(unsigned short*)(sm + base + row * stride + ((col * 2) ^ ((row & 7) << 4))) = v;
}
// plain (any stride)
__device__ __forceinline__ bf16x8 ld8p(const char* sm, int base, int stride, int row, int colbyte) {
  return *(const bf16x8*)(sm + base + row * stride + colbyte);
}
__device__ __forceinline__ void st2p(char* sm, int base, int stride, int row, int col, unsigned short v) {
  *(unsigned short*)(sm + base + row * stride + col * 2) = v;
}
__device__ __forceinline__ float ld2p(const char* sm, int base, int stride, int row, int col) {
  return bf2f(*(const unsigned short*)(sm + base + row * stride + col * 2));
}

__global__ __launch_bounds__(768)
__attribute__((amdgpu_waves_per_eu(3, 3)))
void attn_kernel(
    const float* __restrict__ x, const float* __restrict__ qkv_w,
    const float* __restrict__ proj_w, const float* __restrict__ proj_b,
    const float* __restrict__ dwc_w, const float* __restrict__ dwc_b,
    const float* __restrict__ an, const float* __restrict__ ah,
    const float* __restrict__ aw, const float* __restrict__ na,
    const float* __restrict__ ha, const float* __restrict__ wa,
    float* __restrict__ out)
{
  __shared__ __align__(16) char sm[SMEM_BYTES];
  const int tid = threadIdx.x;
  const int wave = tid >> 6;        // 0..11; mt = wave; wave 11 idle in compute
  const int lane = tid & 63;
  const int l15 = lane & 15;
  const int l4 = lane >> 4;
  const int mt = wave;
  const f32x4 z = {0.f, 0.f, 0.f, 0.f};

  const float* xbp[2];
  float* op[2];
  xbp[0] = x + (size_t)blockIdx.x * 43264;            // 169*256
  xbp[1] = x + (size_t)(blockIdx.x + 512) * 43264;
  op[0] = out + (size_t)blockIdx.x * 43264;
  op[1] = out + (size_t)(blockIdx.x + 512) * 43264;

  // one-time LDS zero: stray bytes must never decode to Inf/NaN
  {
    int* p = (int*)sm;
    for (int i = tid; i < SMEM_BYTES / 4; i += 768) p[i] = 0;
  }

  // fused S-phase (in-reg softmax, shared bias) + PV via per-(wave,bb) P_tmp.
  auto fused = [&](int sOff, int pvOff, int which, int h, f32x4 (&o)[2][4]) {
#pragma unroll
    for (int bb = 0; bb < 2; ++bb)
#pragma unroll
      for (int dt = 0; dt < 4; ++dt) o[bb][dt] = z;
    if (mt >= 11) return;
    const int arow = mt * 16 + l15;
    const int rbase = mt * 16 + l4 * 4;
    bf16x8 a0[2], a1[2];
#pragma unroll
    for (int bb = 0; bb < 2; ++bb) {
      a0[bb] = ld8s(sm, bb * BSTR + OFF_Q, 128, arow, l4 * 16);
      a1[bb] = ld8s(sm, bb * BSTR + OFF_Q, 128, arow, 64 + l4 * 16);
    }
    f32x4 s[2][11];
#pragma unroll
    for (int nt = 0; nt < 11; ++nt) {
      const int brow = nt * 16 + l15;
#pragma unroll
      for (int bb = 0; bb < 2; ++bb) {
        bf16x8 b0 = ld8s(sm, bb * BSTR + sOff, 128, brow, l4 * 16);
        bf16x8 b1 = ld8s(sm, bb * BSTR + sOff, 128, brow, 64 + l4 * 16);
        f32x4 c = z;
        c = mfma16(a0[bb], b0, c);
        c = mfma16(a1[bb], b1, c);
        s[bb][nt] = c;
      }
    }
    // bias (SHARED between the two b's) + mask
#pragma unroll
    for (int nt = 0; nt < 11; ++nt) {
      const int cc = nt * 16 + l15;
      const int ccl = cc > 168 ? 168 : cc;
      const int yc = (ccl * 79) >> 10;
      const int xc = ccl - yc * 13;
#pragma unroll
      for (int r = 0; r < 4; ++r) {
        const int rr = rbase + r;
        const int rrl = rr > 168 ? 168 : rr;
        float bias;
        if (which == 0) {
          bias = an[h * 28561 + rrl * 169 + ccl]
               + ah[(h * 169 + rrl) * 13 + yc]
               + aw[(h * 169 + rrl) * 13 + xc];
        } else {
          const int yn = (rrl * 79) >> 10;
          const int xn = rrl - yn * 13;
          bias = na[h * 28561 + ccl * 169 + rrl]
               + ha[(h * 13 + yn) * 169 + ccl]
               + wa[(h * 13 + xn) * 169 + ccl];
        }
#pragma unroll
        for (int bb = 0; bb < 2; ++bb) {
          const float v = s[bb][nt][r] * 0.125f + bias;
          s[bb][nt][r] = (cc > 168) ? -3.0e38f : v;
        }
      }
    }
    // in-register softmax (two independent chains)
#pragma unroll
    for (int bb = 0; bb < 2; ++bb)
#pragma unroll
      for (int r = 0; r < 4; ++r) {
        float m = s[bb][0][r];
#pragma unroll
        for (int nt = 1; nt < 11; ++nt) m = fmaxf(m, s[bb][nt][r]);
        m = fmaxf(m, __shfl_xor(m, 1));
        m = fmaxf(m, __shfl_xor(m, 2));
        m = fmaxf(m, __shfl_xor(m, 4));
        m = fmaxf(m, __shfl_xor(m, 8));
        float sum = 0.f;
#pragma unroll
        for (int nt = 0; nt < 11; ++nt) { const float e = __expf(s[bb][nt][r] - m); s[bb][nt][r] = e; sum += e; }
        sum += __shfl_xor(sum, 1);
        sum += __shfl_xor(sum, 2);
        sum += __shfl_xor(sum, 4);
        sum += __shfl_xor(sum, 8);
        const float inv = 1.f / sum;
#pragma unroll
        for (int nt = 0; nt < 11; ++nt) s[bb][nt][r] *= inv;
      }
    // PV: per 32-wide chunk pair, through per-(wave,bb) P_tmp
#pragma unroll
    for (int np = 0; np < 6; ++np) {
      const int nt1 = 2 * np + 1;
      bf16x8 af[2];
#pragma unroll
      for (int bb = 0; bb < 2; ++bb) {
        const int tb = OFF_T + (wave * 2 + bb) * 1152;
#pragma unroll
        for (int r = 0; r < 4; ++r) {
          char* prow = sm + tb + (l4 * 4 + r) * 72;
          *(unsigned short*)(prow + l15 * 2) = f2bf(s[bb][2 * np][r]);
          *(unsigned short*)(prow + 32 + l15 * 2) =
              (nt1 < 11) ? f2bf(s[bb][nt1][r]) : (unsigned short)0;
        }
        af[bb] = *(const bf16x8*)(sm + tb + l15 * 72 + l4 * 16);
      }
#pragma unroll
      for (int dt = 0; dt < 4; ++dt)
#pragma unroll
        for (int bb = 0; bb < 2; ++bb) {
          bf16x8 bv = ld8p(sm, bb * BSTR + pvOff, 352, dt * 16 + l15, np * 64 + l4 * 16);
          o[bb][dt] = mfma16(af[bb], bv, o[bb][dt]);
        }
    }
  };

  for (int h = 0; h < 4; ++h) {
    __syncthreads();   // previous head fully consumed (and initial zero done)

    // ---- QKV: [176 x 192] = x[b] @ w_head^T; w-frags SHARED across b ----
    if (mt < 11) {
      f32x4 acc[2][12];
#pragma unroll
      for (int bb = 0; bb < 2; ++bb)
#pragma unroll
        for (int i = 0; i < 12; ++i) acc[bb][i] = z;
      const int arow = mt * 16 + l15;
      const int gr = arow < 169 ? arow : 168;

      for (int ks = 0; ks < 8; ++ks) {
        bf16x8 af[2];
#pragma unroll
        for (int bb = 0; bb < 2; ++bb) {
          const float* p0 = xbp[bb] + gr * 256 + ks * 32 + l4 * 8;
          af[bb] = cvt8(*(const float4*)p0, *(const float4*)(p0 + 4));
        }
#pragma unroll
        for (int nt = 0; nt < 12; ++nt) {
          const int wrow = nt * 16 + l15;
          const int grow = ((wrow >> 6) << 8) + h * 64 + (wrow & 63);
          const float* wp = qkv_w + grow * 256 + ks * 32 + l4 * 8;
          bf16x8 bw = cvt8(*(const float4*)wp, *(const float4*)(wp + 4));   // shared
          acc[0][nt] = mfma16(af[0], bw, acc[0][nt]);
          acc[1][nt] = mfma16(af[1], bw, acc[1][nt]);
        }
      }
      // write Q,K (stride 128, swz); V transposed [d][n] (stride 352, plain)
#pragma unroll
      for (int nt = 0; nt < 12; ++nt) {
        const int mat = nt >> 2;
        const int d = (nt & 3) * 16 + l15;
#pragma unroll
        for (int r = 0; r < 4; ++r) {
          const int n = mt * 16 + l4 * 4 + r;
#pragma unroll
          for (int bb = 0; bb < 2; ++bb) {
            const unsigned short u = f2bf(acc[bb][nt][r]);
            if (mat == 0)      st2s(sm, bb * BSTR + OFF_Q, 128, n, d, u);
            else if (mat == 1) st2s(sm, bb * BSTR + OFF_K, 128, n, d, u);
            else               st2p(sm, bb * BSTR + OFF_V, 352, d, n, u);
          }
        }
      }
    }
    __syncthreads();

    // ---- S1 + P1V fused (B=K, PV-B=Vt) -> agent_v rows in regs ----
    f32x4 o1[2][4];
    fused(OFF_K, OFF_V, 0, h, o1);
    __syncthreads();                 // all S1 reads of K done
    // write avT [d][a] over K region (stride 352, plain)
    if (mt < 11) {
#pragma unroll
      for (int bb = 0; bb < 2; ++bb)
#pragma unroll
        for (int dt = 0; dt < 4; ++dt)
#pragma unroll
          for (int r = 0; r < 4; ++r)
            st2p(sm, bb * BSTR + OFF_K, 352, dt * 16 + l15, mt * 16 + l4 * 4 + r,
                 f2bf(o1[bb][dt][r]));
    }
    __syncthreads();

    // ---- S2 + P2A fused (B=Q, PV-B=avT) + dwconv epilogue (reads Vt) ----
    f32x4 o2[2][4];
    fused(OFF_Q, OFF_K, 1, h, o2);
    if (mt < 11) {
#pragma unroll
      for (int dt = 0; dt < 4; ++dt) {
        const int d = dt * 16 + l15;
        const int c = h * 64 + d;
        const float bc = dwc_b[c];
#pragma unroll
        for (int r = 0; r < 4; ++r) {
          const int n = mt * 16 + l4 * 4 + r;
          const int nl = n > 168 ? 168 : n;
          const int y = (nl * 79) >> 10;
          const int xx = nl - y * 13;
          float dw0 = bc, dw1 = bc;
#pragma unroll
          for (int ky = 0; ky < 3; ++ky) {
            const int yy = y + ky - 1;
            if ((unsigned)yy >= 13u) continue;
#pragma unroll
            for (int kx = 0; kx < 3; ++kx) {
              const int x2 = xx + kx - 1;
              if ((unsigned)x2 >= 13u) continue;
              const float wv = dwc_w[c * 9 + ky * 3 + kx];   // shared
              dw0 += wv * ld2p(sm, 0 * BSTR + OFF_V, 352, d, yy * 13 + x2);
              dw1 += wv * ld2p(sm, 1 * BSTR + OFF_V, 352, d, yy * 13 + x2);
            }
          }
          o2[0][dt][r] += dw0;
          o2[1][dt][r] += dw1;
        }
      }
    }
    __syncthreads();                 // all dwconv reads of Vt done

    // ---- write act [n][d] over Vt region (stride 128, swz) + stage Wproj ----
    if (mt < 11) {
#pragma unroll
      for (int bb = 0; bb < 2; ++bb)
#pragma unroll
        for (int dt = 0; dt < 4; ++dt) {
          const int d = dt * 16 + l15;
#pragma unroll
          for (int r = 0; r < 4; ++r)
            st2s(sm, bb * BSTR + OFF_V, 128, mt * 16 + l4 * 4 + r, d, f2bf(o2[bb][dt][r]));
        }
    }
    // Wproj [256 rows][64 d] bf16 stride 128 swz at absolute 0..32768
    // (covers b0 Q + part of b0 K/avT -- both dead in proj phase), SHARED.
    for (int idx = tid; idx < 2048; idx += 768) {
      const int j = idx >> 3;          // 0..255
      const int c8 = idx & 7;
      const float* src = proj_w + j * 256 + h * 64 + c8 * 8;
      float4 f0 = *(const float4*)(src);
      float4 f1 = *(const float4*)(src + 4);
      *(bf16x8*)(sm + j * 128 + ((c8 * 16) ^ ((j & 7) << 4))) = cvt8(f0, f1);
    }
    __syncthreads();

    // ---- proj partial MFMA: out (+)= act @ Wproj^T (K=64), fp32 RMW ----
    if (mt < 11) {
      const int arow = mt * 16 + l15;
      bf16x8 af0[2], af1[2];
#pragma unroll
      for (int bb = 0; bb < 2; ++bb) {
        af0[bb] = ld8s(sm, bb * BSTR + OFF_V, 128, arow, l4 * 16);
        af1[bb] = ld8s(sm, bb * BSTR + OFF_V, 128, arow, 64 + l4 * 16);
      }
#pragma unroll
      for (int nt = 0; nt < 16; ++nt) {
        const int brow = nt * 16 + l15;
        bf16x8 bf0 = ld8s(sm, 0, 128, brow, l4 * 16);        // shared
        bf16x8 bf1 = ld8s(sm, 0, 128, brow, 64 + l4 * 16);
        const int col = nt * 16 + l15;
#pragma unroll
        for (int bb = 0; bb < 2; ++bb) {
          f32x4 c = z;
          c = mfma16(af0[bb], bf0, c);
          c = mfma16(af1[bb], bf1, c);
#pragma unroll
          for (int r = 0; r < 4; ++r) {
            const int n = mt * 16 + l4 * 4 + r;
            if (n < 169) {
              float* p = op[bb] + (size_t)n * 256 + col;
              if (h == 0)      *p = c[r] + proj_b[col];
              else if (h == 3) __builtin_nontemporal_store(*p + c[r], p);
              else             *p += c[r];
            }
          }
        }
      }
    }
    // next head's loop-top barrier protects Q/K/V regions
  }
}

extern "C" void kernel_launch(void* const* d_in, const int* in_sizes, int n_in,
                              void* d_out, int out_size, void* d_ws, size_t ws_size,
                              hipStream_t stream) {
  const float* x      = (const float*)d_in[0];
  const float* qkv_w  = (const float*)d_in[1];
  const float* proj_w = (const float*)d_in[2];
  const float* proj_b = (const float*)d_in[3];
  const float* dwc_w  = (const float*)d_in[4];
  const float* dwc_b  = (const float*)d_in[5];
  const float* an     = (const float*)d_in[6];
  const float* na     = (const float*)d_in[7];
  const float* ah     = (const float*)d_in[8];
  const float* aw     = (const float*)d_in[9];
  const float* ha     = (const float*)d_in[10];
  const float* wa     = (const float*)d_in[11];

  attn_kernel<<<512, 768, 0, stream>>>(
      x, qkv_w, proj_w, proj_b, dwc_w, dwc_b,
      an, ah, aw, na, ha, wa, (float*)d_out);
}

// Round 18
// 2211.708 us; speedup vs baseline: 1.1822x; 1.0357x over previous
//
#include <hip/hip_runtime.h>

// Round 18: round 17's compile fix (nontemporal builtins need native vector
// types, not HIP_vector_type float4 -> use ext_vector f32x4). Mechanism
// unchanged: NT hints on streaming traffic (x loads, out RMW) so the shared
// tables (qkv_w/biases/proj_w) stay L2-resident.

typedef __attribute__((ext_vector_type(8))) short bf16x8;
typedef __attribute__((ext_vector_type(4))) float f32x4;

#define BSTR  67584      // per-b region: Q[0,22528) K/avT[22528,45056) V/act[45056,67584)
#define OFF_Q 0
#define OFF_K 22528
#define OFF_V 45056
#define OFF_T 135168     // P_tmp: per (wave,bb) 1152B = [16][36 bf16] stride 72
#define SMEM_BYTES 162816

__device__ __forceinline__ unsigned short f2bf(float f) {
  unsigned int u = __float_as_uint(f);
  u += 0x7FFFu + ((u >> 16) & 1u);
  return (unsigned short)(u >> 16);
}
__device__ __forceinline__ float bf2f(unsigned short v) {
  return __uint_as_float(((unsigned int)v) << 16);
}
__device__ __forceinline__ f32x4 mfma16(bf16x8 a, bf16x8 b, f32x4 c) {
  return __builtin_amdgcn_mfma_f32_16x16x32_bf16(a, b, c, 0, 0, 0);
}
__device__ __forceinline__ bf16x8 cvt8(float4 a, float4 b) {
  bf16x8 v;
  v[0] = (short)f2bf(a.x); v[1] = (short)f2bf(a.y);
  v[2] = (short)f2bf(a.z); v[3] = (short)f2bf(a.w);
  v[4] = (short)f2bf(b.x); v[5] = (short)f2bf(b.y);
  v[6] = (short)f2bf(b.z); v[7] = (short)f2bf(b.w);
  return v;
}
__device__ __forceinline__ bf16x8 cvt8v(f32x4 a, f32x4 b) {
  bf16x8 v;
  v[0] = (short)f2bf(a[0]); v[1] = (short)f2bf(a[1]);
  v[2] = (short)f2bf(a[2]); v[3] = (short)f2bf(a[3]);
  v[4] = (short)f2bf(b[0]); v[5] = (short)f2bf(b[1]);
  v[6] = (short)f2bf(b[2]); v[7] = (short)f2bf(b[3]);
  return v;
}
__device__ __forceinline__ f32x4 ntld4(const float* p) {
  return __builtin_nontemporal_load(reinterpret_cast<const f32x4*>(p));
}
// swizzled (stride multiple of 128; base multiple of 128)
__device__ __forceinline__ bf16x8 ld8s(const char* sm, int base, int stride, int row, int colbyte) {
  return *(const bf16x8*)(sm + base + row * stride + (colbyte ^ ((row & 7) << 4)));
}
__device__ __forceinline__ void st2s(char* sm, int base, int stride, int row, int col, unsigned short v) {
  *(unsigned short*)(sm + base + row * stride + ((col * 2) ^ ((row & 7) << 4))) = v;
}
// plain (any stride)
__device__ __forceinline__ bf16x8 ld8p(const char* sm, int base, int stride, int row, int colbyte) {
  return *(const bf16x8*)(sm + base + row * stride + colbyte);
}
__device__ __forceinline__ void st2p(char* sm, int base, int stride, int row, int col, unsigned short v) {
  *(unsigned short*)(sm + base + row * stride + col * 2) = v;
}
__device__ __forceinline__ float ld2p(const char* sm, int base, int stride, int row, int col) {
  return bf2f(*(const unsigned short*)(sm + base + row * stride + col * 2));
}

__global__ __launch_bounds__(768)
__attribute__((amdgpu_waves_per_eu(3, 3)))
void attn_kernel(
    const float* __restrict__ x, const float* __restrict__ qkv_w,
    const float* __restrict__ proj_w, const float* __restrict__ proj_b,
    const float* __restrict__ dwc_w, const float* __restrict__ dwc_b,
    const float* __restrict__ an, const float* __restrict__ ah,
    const float* __restrict__ aw, const float* __restrict__ na,
    const float* __restrict__ ha, const float* __restrict__ wa,
    float* __restrict__ out)
{
  __shared__ __align__(16) char sm[SMEM_BYTES];
  const int tid = threadIdx.x;
  const int wave = tid >> 6;        // 0..11; mt = wave; wave 11 idle in compute
  const int lane = tid & 63;
  const int l15 = lane & 15;
  const int l4 = lane >> 4;
  const int mt = wave;
  const f32x4 z = {0.f, 0.f, 0.f, 0.f};

  const float* xbp[2];
  float* op[2];
  xbp[0] = x + (size_t)blockIdx.x * 43264;            // 169*256
  xbp[1] = x + (size_t)(blockIdx.x + 512) * 43264;
  op[0] = out + (size_t)blockIdx.x * 43264;
  op[1] = out + (size_t)(blockIdx.x + 512) * 43264;

  // one-time LDS zero: stray bytes must never decode to Inf/NaN
  {
    int* p = (int*)sm;
    for (int i = tid; i < SMEM_BYTES / 4; i += 768) p[i] = 0;
  }

  // fused S-phase (in-reg softmax, shared bias) + PV via per-(wave,bb) P_tmp.
  auto fused = [&](int sOff, int pvOff, int which, int h, f32x4 (&o)[2][4]) {
#pragma unroll
    for (int bb = 0; bb < 2; ++bb)
#pragma unroll
      for (int dt = 0; dt < 4; ++dt) o[bb][dt] = z;
    if (mt >= 11) return;
    const int arow = mt * 16 + l15;
    const int rbase = mt * 16 + l4 * 4;
    bf16x8 a0[2], a1[2];
#pragma unroll
    for (int bb = 0; bb < 2; ++bb) {
      a0[bb] = ld8s(sm, bb * BSTR + OFF_Q, 128, arow, l4 * 16);
      a1[bb] = ld8s(sm, bb * BSTR + OFF_Q, 128, arow, 64 + l4 * 16);
    }
    f32x4 s[2][11];
#pragma unroll
    for (int nt = 0; nt < 11; ++nt) {
      const int brow = nt * 16 + l15;
#pragma unroll
      for (int bb = 0; bb < 2; ++bb) {
        bf16x8 b0 = ld8s(sm, bb * BSTR + sOff, 128, brow, l4 * 16);
        bf16x8 b1 = ld8s(sm, bb * BSTR + sOff, 128, brow, 64 + l4 * 16);
        f32x4 c = z;
        c = mfma16(a0[bb], b0, c);
        c = mfma16(a1[bb], b1, c);
        s[bb][nt] = c;
      }
    }
    // bias (SHARED between the two b's) + mask
#pragma unroll
    for (int nt = 0; nt < 11; ++nt) {
      const int cc = nt * 16 + l15;
      const int ccl = cc > 168 ? 168 : cc;
      const int yc = (ccl * 79) >> 10;
      const int xc = ccl - yc * 13;
#pragma unroll
      for (int r = 0; r < 4; ++r) {
        const int rr = rbase + r;
        const int rrl = rr > 168 ? 168 : rr;
        float bias;
        if (which == 0) {
          bias = an[h * 28561 + rrl * 169 + ccl]
               + ah[(h * 169 + rrl) * 13 + yc]
               + aw[(h * 169 + rrl) * 13 + xc];
        } else {
          const int yn = (rrl * 79) >> 10;
          const int xn = rrl - yn * 13;
          bias = na[h * 28561 + ccl * 169 + rrl]
               + ha[(h * 13 + yn) * 169 + ccl]
               + wa[(h * 13 + xn) * 169 + ccl];
        }
#pragma unroll
        for (int bb = 0; bb < 2; ++bb) {
          const float v = s[bb][nt][r] * 0.125f + bias;
          s[bb][nt][r] = (cc > 168) ? -3.0e38f : v;
        }
      }
    }
    // in-register softmax (two independent chains)
#pragma unroll
    for (int bb = 0; bb < 2; ++bb)
#pragma unroll
      for (int r = 0; r < 4; ++r) {
        float m = s[bb][0][r];
#pragma unroll
        for (int nt = 1; nt < 11; ++nt) m = fmaxf(m, s[bb][nt][r]);
        m = fmaxf(m, __shfl_xor(m, 1));
        m = fmaxf(m, __shfl_xor(m, 2));
        m = fmaxf(m, __shfl_xor(m, 4));
        m = fmaxf(m, __shfl_xor(m, 8));
        float sum = 0.f;
#pragma unroll
        for (int nt = 0; nt < 11; ++nt) { const float e = __expf(s[bb][nt][r] - m); s[bb][nt][r] = e; sum += e; }
        sum += __shfl_xor(sum, 1);
        sum += __shfl_xor(sum, 2);
        sum += __shfl_xor(sum, 4);
        sum += __shfl_xor(sum, 8);
        const float inv = 1.f / sum;
#pragma unroll
        for (int nt = 0; nt < 11; ++nt) s[bb][nt][r] *= inv;
      }
    // PV: per 32-wide chunk pair, through per-(wave,bb) P_tmp
#pragma unroll
    for (int np = 0; np < 6; ++np) {
      const int nt1 = 2 * np + 1;
      bf16x8 af[2];
#pragma unroll
      for (int bb = 0; bb < 2; ++bb) {
        const int tb = OFF_T + (wave * 2 + bb) * 1152;
#pragma unroll
        for (int r = 0; r < 4; ++r) {
          char* prow = sm + tb + (l4 * 4 + r) * 72;
          *(unsigned short*)(prow + l15 * 2) = f2bf(s[bb][2 * np][r]);
          *(unsigned short*)(prow + 32 + l15 * 2) =
              (nt1 < 11) ? f2bf(s[bb][nt1][r]) : (unsigned short)0;
        }
        af[bb] = *(const bf16x8*)(sm + tb + l15 * 72 + l4 * 16);
      }
#pragma unroll
      for (int dt = 0; dt < 4; ++dt)
#pragma unroll
        for (int bb = 0; bb < 2; ++bb) {
          bf16x8 bv = ld8p(sm, bb * BSTR + pvOff, 352, dt * 16 + l15, np * 64 + l4 * 16);
          o[bb][dt] = mfma16(af[bb], bv, o[bb][dt]);
        }
    }
  };

  for (int h = 0; h < 4; ++h) {
    __syncthreads();   // previous head fully consumed (and initial zero done)

    // ---- QKV: [176 x 192] = x[b] @ w_head^T; w-frags SHARED across b ----
    if (mt < 11) {
      f32x4 acc[2][12];
#pragma unroll
      for (int bb = 0; bb < 2; ++bb)
#pragma unroll
        for (int i = 0; i < 12; ++i) acc[bb][i] = z;
      const int arow = mt * 16 + l15;
      const int gr = arow < 169 ? arow : 168;

      for (int ks = 0; ks < 8; ++ks) {
        bf16x8 af[2];
#pragma unroll
        for (int bb = 0; bb < 2; ++bb) {
          const float* p0 = xbp[bb] + gr * 256 + ks * 32 + l4 * 8;
          af[bb] = cvt8v(ntld4(p0), ntld4(p0 + 4));         // NT: streaming x
        }
#pragma unroll
        for (int nt = 0; nt < 12; ++nt) {
          const int wrow = nt * 16 + l15;
          const int grow = ((wrow >> 6) << 8) + h * 64 + (wrow & 63);
          const float* wp = qkv_w + grow * 256 + ks * 32 + l4 * 8;
          bf16x8 bw = cvt8(*(const float4*)wp, *(const float4*)(wp + 4));   // cached: shared table
          acc[0][nt] = mfma16(af[0], bw, acc[0][nt]);
          acc[1][nt] = mfma16(af[1], bw, acc[1][nt]);
        }
      }
      // write Q,K (stride 128, swz); V transposed [d][n] (stride 352, plain)
#pragma unroll
      for (int nt = 0; nt < 12; ++nt) {
        const int mat = nt >> 2;
        const int d = (nt & 3) * 16 + l15;
#pragma unroll
        for (int r = 0; r < 4; ++r) {
          const int n = mt * 16 + l4 * 4 + r;
#pragma unroll
          for (int bb = 0; bb < 2; ++bb) {
            const unsigned short u = f2bf(acc[bb][nt][r]);
            if (mat == 0)      st2s(sm, bb * BSTR + OFF_Q, 128, n, d, u);
            else if (mat == 1) st2s(sm, bb * BSTR + OFF_K, 128, n, d, u);
            else               st2p(sm, bb * BSTR + OFF_V, 352, d, n, u);
          }
        }
      }
    }
    __syncthreads();

    // ---- S1 + P1V fused (B=K, PV-B=Vt) -> agent_v rows in regs ----
    f32x4 o1[2][4];
    fused(OFF_K, OFF_V, 0, h, o1);
    __syncthreads();                 // all S1 reads of K done
    // write avT [d][a] over K region (stride 352, plain)
    if (mt < 11) {
#pragma unroll
      for (int bb = 0; bb < 2; ++bb)
#pragma unroll
        for (int dt = 0; dt < 4; ++dt)
#pragma unroll
          for (int r = 0; r < 4; ++r)
            st2p(sm, bb * BSTR + OFF_K, 352, dt * 16 + l15, mt * 16 + l4 * 4 + r,
                 f2bf(o1[bb][dt][r]));
    }
    __syncthreads();

    // ---- S2 + P2A fused (B=Q, PV-B=avT) + dwconv epilogue (reads Vt) ----
    f32x4 o2[2][4];
    fused(OFF_Q, OFF_K, 1, h, o2);
    if (mt < 11) {
#pragma unroll
      for (int dt = 0; dt < 4; ++dt) {
        const int d = dt * 16 + l15;
        const int c = h * 64 + d;
        const float bc = dwc_b[c];
#pragma unroll
        for (int r = 0; r < 4; ++r) {
          const int n = mt * 16 + l4 * 4 + r;
          const int nl = n > 168 ? 168 : n;
          const int y = (nl * 79) >> 10;
          const int xx = nl - y * 13;
          float dw0 = bc, dw1 = bc;
#pragma unroll
          for (int ky = 0; ky < 3; ++ky) {
            const int yy = y + ky - 1;
            if ((unsigned)yy >= 13u) continue;
#pragma unroll
            for (int kx = 0; kx < 3; ++kx) {
              const int x2 = xx + kx - 1;
              if ((unsigned)x2 >= 13u) continue;
              const float wv = dwc_w[c * 9 + ky * 3 + kx];   // cached: shared table
              dw0 += wv * ld2p(sm, 0 * BSTR + OFF_V, 352, d, yy * 13 + x2);
              dw1 += wv * ld2p(sm, 1 * BSTR + OFF_V, 352, d, yy * 13 + x2);
            }
          }
          o2[0][dt][r] += dw0;
          o2[1][dt][r] += dw1;
        }
      }
    }
    __syncthreads();                 // all dwconv reads of Vt done

    // ---- write act [n][d] over Vt region (stride 128, swz) + stage Wproj ----
    if (mt < 11) {
#pragma unroll
      for (int bb = 0; bb < 2; ++bb)
#pragma unroll
        for (int dt = 0; dt < 4; ++dt) {
          const int d = dt * 16 + l15;
#pragma unroll
          for (int r = 0; r < 4; ++r)
            st2s(sm, bb * BSTR + OFF_V, 128, mt * 16 + l4 * 4 + r, d, f2bf(o2[bb][dt][r]));
        }
    }
    // Wproj [256 rows][64 d] bf16 stride 128 swz at absolute 0..32768
    // (covers b0 Q + part of b0 K/avT -- both dead in proj phase), SHARED.
    for (int idx = tid; idx < 2048; idx += 768) {
      const int j = idx >> 3;          // 0..255
      const int c8 = idx & 7;
      const float* src = proj_w + j * 256 + h * 64 + c8 * 8;
      float4 f0 = *(const float4*)(src);
      float4 f1 = *(const float4*)(src + 4);
      *(bf16x8*)(sm + j * 128 + ((c8 * 16) ^ ((j & 7) << 4))) = cvt8(f0, f1);
    }
    __syncthreads();

    // ---- proj partial MFMA: out (+)= act @ Wproj^T (K=64), fp32 NT-RMW ----
    if (mt < 11) {
      const int arow = mt * 16 + l15;
      bf16x8 af0[2], af1[2];
#pragma unroll
      for (int bb = 0; bb < 2; ++bb) {
        af0[bb] = ld8s(sm, bb * BSTR + OFF_V, 128, arow, l4 * 16);
        af1[bb] = ld8s(sm, bb * BSTR + OFF_V, 128, arow, 64 + l4 * 16);
      }
#pragma unroll
      for (int nt = 0; nt < 16; ++nt) {
        const int brow = nt * 16 + l15;
        bf16x8 bf0 = ld8s(sm, 0, 128, brow, l4 * 16);        // shared
        bf16x8 bf1 = ld8s(sm, 0, 128, brow, 64 + l4 * 16);
        const int col = nt * 16 + l15;
#pragma unroll
        for (int bb = 0; bb < 2; ++bb) {
          f32x4 c = z;
          c = mfma16(af0[bb], bf0, c);
          c = mfma16(af1[bb], bf1, c);
#pragma unroll
          for (int r = 0; r < 4; ++r) {
            const int n = mt * 16 + l4 * 4 + r;
            if (n < 169) {
              float* p = op[bb] + (size_t)n * 256 + col;
              if (h == 0) {
                __builtin_nontemporal_store(c[r] + proj_b[col], p);
              } else {
                const float oldv = __builtin_nontemporal_load(p);
                __builtin_nontemporal_store(oldv + c[r], p);
              }
            }
          }
        }
      }
    }
    // next head's loop-top barrier protects Q/K/V regions
  }
}

extern "C" void kernel_launch(void* const* d_in, const int* in_sizes, int n_in,
                              void* d_out, int out_size, void* d_ws, size_t ws_size,
                              hipStream_t stream) {
  const float* x      = (const float*)d_in[0];
  const float* qkv_w  = (const float*)d_in[1];
  const float* proj_w = (const float*)d_in[2];
  const float* proj_b = (const float*)d_in[3];
  const float* dwc_w  = (const float*)d_in[4];
  const float* dwc_b  = (const float*)d_in[5];
  const float* an     = (const float*)d_in[6];
  const float* na     = (const float*)d_in[7];
  const float* ah     = (const float*)d_in[8];
  const float* aw     = (const float*)d_in[9];
  const float* ha     = (const float*)d_in[10];
  const float* wa     = (const float*)d_in[11];

  attn_kernel<<<512, 768, 0, stream>>>(
      x, qkv_w, proj_w, proj_b, dwc_w, dwc_b,
      an, ah, aw, na, ha, wa, (float*)d_out);
}

// Round 19
// 1552.971 us; speedup vs baseline: 1.6837x; 1.4242x over previous
//
#include <hip/hip_runtime.h>

// Round 19: split proj out of the per-head serial chain.
//  attn_kernel (grid 512, 768 thr): per head ends by storing act (post-dwconv,
//    fp32) straight into d_out[b][n][h*64+d] -- written once, never RMW'd.
//    x loads back to cached (L2-resident; NT was wrong). No Wproj/proj phase.
//  proj_kernel (grid 1352, 512 thr): in-place GEMM -- each block reads ITS OWN
//    128 act rows (fp32) from d_out, computes act @ proj_w^T + proj_b (K=256),
//    overwrites the same 128 rows. All reads precede the single write; blocks
//    touch disjoint rows -> race-free. LDS stride 80 (no XOR swizzle).

typedef __attribute__((ext_vector_type(8))) short bf16x8;
typedef __attribute__((ext_vector_type(4))) float f32x4;

#define BSTR  67584      // per-b region: Q[0,22528) K/avT[22528,45056) V[45056,67584)
#define OFF_Q 0
#define OFF_K 22528
#define OFF_V 45056
#define OFF_T 135168     // P_tmp: per (wave,bb) 1152B = [16][36 bf16] stride 72
#define SMEM_BYTES 162816

__device__ __forceinline__ unsigned short f2bf(float f) {
  unsigned int u = __float_as_uint(f);
  u += 0x7FFFu + ((u >> 16) & 1u);
  return (unsigned short)(u >> 16);
}
__device__ __forceinline__ float bf2f(unsigned short v) {
  return __uint_as_float(((unsigned int)v) << 16);
}
__device__ __forceinline__ f32x4 mfma16(bf16x8 a, bf16x8 b, f32x4 c) {
  return __builtin_amdgcn_mfma_f32_16x16x32_bf16(a, b, c, 0, 0, 0);
}
__device__ __forceinline__ bf16x8 cvt8(float4 a, float4 b) {
  bf16x8 v;
  v[0] = (short)f2bf(a.x); v[1] = (short)f2bf(a.y);
  v[2] = (short)f2bf(a.z); v[3] = (short)f2bf(a.w);
  v[4] = (short)f2bf(b.x); v[5] = (short)f2bf(b.y);
  v[6] = (short)f2bf(b.z); v[7] = (short)f2bf(b.w);
  return v;
}
// swizzled (stride multiple of 128; base multiple of 128)
__device__ __forceinline__ bf16x8 ld8s(const char* sm, int base, int stride, int row, int colbyte) {
  return *(const bf16x8*)(sm + base + row * stride + (colbyte ^ ((row & 7) << 4)));
}
__device__ __forceinline__ void st2s(char* sm, int base, int stride, int row, int col, unsigned short v) {
  *(unsigned short*)(sm + base + row * stride + ((col * 2) ^ ((row & 7) << 4))) = v;
}
// plain (any stride)
__device__ __forceinline__ bf16x8 ld8p(const char* sm, int base, int stride, int row, int colbyte) {
  return *(const bf16x8*)(sm + base + row * stride + colbyte);
}
__device__ __forceinline__ void st2p(char* sm, int base, int stride, int row, int col, unsigned short v) {
  *(unsigned short*)(sm + base + row * stride + col * 2) = v;
}
__device__ __forceinline__ float ld2p(const char* sm, int base, int stride, int row, int col) {
  return bf2f(*(const unsigned short*)(sm + base + row * stride + col * 2));
}

__global__ __launch_bounds__(768) void attn_kernel(
    const float* __restrict__ x, const float* __restrict__ qkv_w,
    const float* __restrict__ dwc_w, const float* __restrict__ dwc_b,
    const float* __restrict__ an, const float* __restrict__ ah,
    const float* __restrict__ aw, const float* __restrict__ na,
    const float* __restrict__ ha, const float* __restrict__ wa,
    float* __restrict__ out)
{
  __shared__ __align__(16) char sm[SMEM_BYTES];
  const int tid = threadIdx.x;
  const int wave = tid >> 6;        // 0..11; mt = wave; wave 11 idle in compute
  const int lane = tid & 63;
  const int l15 = lane & 15;
  const int l4 = lane >> 4;
  const int mt = wave;
  const f32x4 z = {0.f, 0.f, 0.f, 0.f};

  const float* xbp[2];
  float* op[2];
  xbp[0] = x + (size_t)blockIdx.x * 43264;            // 169*256
  xbp[1] = x + (size_t)(blockIdx.x + 512) * 43264;
  op[0] = out + (size_t)blockIdx.x * 43264;
  op[1] = out + (size_t)(blockIdx.x + 512) * 43264;

  // one-time LDS zero: stray bytes must never decode to Inf/NaN
  {
    int* p = (int*)sm;
    for (int i = tid; i < SMEM_BYTES / 4; i += 768) p[i] = 0;
  }

  // fused S-phase (in-reg softmax, shared bias) + PV via per-(wave,bb) P_tmp.
  auto fused = [&](int sOff, int pvOff, int which, int h, f32x4 (&o)[2][4]) {
#pragma unroll
    for (int bb = 0; bb < 2; ++bb)
#pragma unroll
      for (int dt = 0; dt < 4; ++dt) o[bb][dt] = z;
    if (mt >= 11) return;
    const int arow = mt * 16 + l15;
    const int rbase = mt * 16 + l4 * 4;
    bf16x8 a0[2], a1[2];
#pragma unroll
    for (int bb = 0; bb < 2; ++bb) {
      a0[bb] = ld8s(sm, bb * BSTR + OFF_Q, 128, arow, l4 * 16);
      a1[bb] = ld8s(sm, bb * BSTR + OFF_Q, 128, arow, 64 + l4 * 16);
    }
    f32x4 s[2][11];
#pragma unroll
    for (int nt = 0; nt < 11; ++nt) {
      const int brow = nt * 16 + l15;
#pragma unroll
      for (int bb = 0; bb < 2; ++bb) {
        bf16x8 b0 = ld8s(sm, bb * BSTR + sOff, 128, brow, l4 * 16);
        bf16x8 b1 = ld8s(sm, bb * BSTR + sOff, 128, brow, 64 + l4 * 16);
        f32x4 c = z;
        c = mfma16(a0[bb], b0, c);
        c = mfma16(a1[bb], b1, c);
        s[bb][nt] = c;
      }
    }
    // bias (SHARED between the two b's) + mask
#pragma unroll
    for (int nt = 0; nt < 11; ++nt) {
      const int cc = nt * 16 + l15;
      const int ccl = cc > 168 ? 168 : cc;
      const int yc = (ccl * 79) >> 10;
      const int xc = ccl - yc * 13;
#pragma unroll
      for (int r = 0; r < 4; ++r) {
        const int rr = rbase + r;
        const int rrl = rr > 168 ? 168 : rr;
        float bias;
        if (which == 0) {
          bias = an[h * 28561 + rrl * 169 + ccl]
               + ah[(h * 169 + rrl) * 13 + yc]
               + aw[(h * 169 + rrl) * 13 + xc];
        } else {
          const int yn = (rrl * 79) >> 10;
          const int xn = rrl - yn * 13;
          bias = na[h * 28561 + ccl * 169 + rrl]
               + ha[(h * 13 + yn) * 169 + ccl]
               + wa[(h * 13 + xn) * 169 + ccl];
        }
#pragma unroll
        for (int bb = 0; bb < 2; ++bb) {
          const float v = s[bb][nt][r] * 0.125f + bias;
          s[bb][nt][r] = (cc > 168) ? -3.0e38f : v;
        }
      }
    }
    // in-register softmax (two independent chains)
#pragma unroll
    for (int bb = 0; bb < 2; ++bb)
#pragma unroll
      for (int r = 0; r < 4; ++r) {
        float m = s[bb][0][r];
#pragma unroll
        for (int nt = 1; nt < 11; ++nt) m = fmaxf(m, s[bb][nt][r]);
        m = fmaxf(m, __shfl_xor(m, 1));
        m = fmaxf(m, __shfl_xor(m, 2));
        m = fmaxf(m, __shfl_xor(m, 4));
        m = fmaxf(m, __shfl_xor(m, 8));
        float sum = 0.f;
#pragma unroll
        for (int nt = 0; nt < 11; ++nt) { const float e = __expf(s[bb][nt][r] - m); s[bb][nt][r] = e; sum += e; }
        sum += __shfl_xor(sum, 1);
        sum += __shfl_xor(sum, 2);
        sum += __shfl_xor(sum, 4);
        sum += __shfl_xor(sum, 8);
        const float inv = 1.f / sum;
#pragma unroll
        for (int nt = 0; nt < 11; ++nt) s[bb][nt][r] *= inv;
      }
    // PV: per 32-wide chunk pair, through per-(wave,bb) P_tmp
#pragma unroll
    for (int np = 0; np < 6; ++np) {
      const int nt1 = 2 * np + 1;
      bf16x8 af[2];
#pragma unroll
      for (int bb = 0; bb < 2; ++bb) {
        const int tb = OFF_T + (wave * 2 + bb) * 1152;
#pragma unroll
        for (int r = 0; r < 4; ++r) {
          char* prow = sm + tb + (l4 * 4 + r) * 72;
          *(unsigned short*)(prow + l15 * 2) = f2bf(s[bb][2 * np][r]);
          *(unsigned short*)(prow + 32 + l15 * 2) =
              (nt1 < 11) ? f2bf(s[bb][nt1][r]) : (unsigned short)0;
        }
        af[bb] = *(const bf16x8*)(sm + tb + l15 * 72 + l4 * 16);
      }
#pragma unroll
      for (int dt = 0; dt < 4; ++dt)
#pragma unroll
        for (int bb = 0; bb < 2; ++bb) {
          bf16x8 bv = ld8p(sm, bb * BSTR + pvOff, 352, dt * 16 + l15, np * 64 + l4 * 16);
          o[bb][dt] = mfma16(af[bb], bv, o[bb][dt]);
        }
    }
  };

  for (int h = 0; h < 4; ++h) {
    __syncthreads();   // previous head fully consumed (and initial zero done)

    // ---- QKV: [176 x 192] = x[b] @ w_head^T; w-frags SHARED across b ----
    if (mt < 11) {
      f32x4 acc[2][12];
#pragma unroll
      for (int bb = 0; bb < 2; ++bb)
#pragma unroll
        for (int i = 0; i < 12; ++i) acc[bb][i] = z;
      const int arow = mt * 16 + l15;
      const int gr = arow < 169 ? arow : 168;

      for (int ks = 0; ks < 8; ++ks) {
        bf16x8 af[2];
#pragma unroll
        for (int bb = 0; bb < 2; ++bb) {
          const float* p0 = xbp[bb] + gr * 256 + ks * 32 + l4 * 8;
          af[bb] = cvt8(*(const float4*)p0, *(const float4*)(p0 + 4));  // cached
        }
#pragma unroll
        for (int nt = 0; nt < 12; ++nt) {
          const int wrow = nt * 16 + l15;
          const int grow = ((wrow >> 6) << 8) + h * 64 + (wrow & 63);
          const float* wp = qkv_w + grow * 256 + ks * 32 + l4 * 8;
          bf16x8 bw = cvt8(*(const float4*)wp, *(const float4*)(wp + 4));   // shared table
          acc[0][nt] = mfma16(af[0], bw, acc[0][nt]);
          acc[1][nt] = mfma16(af[1], bw, acc[1][nt]);
        }
      }
      // write Q,K (stride 128, swz); V transposed [d][n] (stride 352, plain)
#pragma unroll
      for (int nt = 0; nt < 12; ++nt) {
        const int mat = nt >> 2;
        const int d = (nt & 3) * 16 + l15;
#pragma unroll
        for (int r = 0; r < 4; ++r) {
          const int n = mt * 16 + l4 * 4 + r;
#pragma unroll
          for (int bb = 0; bb < 2; ++bb) {
            const unsigned short u = f2bf(acc[bb][nt][r]);
            if (mat == 0)      st2s(sm, bb * BSTR + OFF_Q, 128, n, d, u);
            else if (mat == 1) st2s(sm, bb * BSTR + OFF_K, 128, n, d, u);
            else               st2p(sm, bb * BSTR + OFF_V, 352, d, n, u);
          }
        }
      }
    }
    __syncthreads();

    // ---- S1 + P1V fused (B=K, PV-B=Vt) -> agent_v rows in regs ----
    f32x4 o1[2][4];
    fused(OFF_K, OFF_V, 0, h, o1);
    __syncthreads();                 // all S1 reads of K done
    // write avT [d][a] over K region (stride 352, plain)
    if (mt < 11) {
#pragma unroll
      for (int bb = 0; bb < 2; ++bb)
#pragma unroll
        for (int dt = 0; dt < 4; ++dt)
#pragma unroll
          for (int r = 0; r < 4; ++r)
            st2p(sm, bb * BSTR + OFF_K, 352, dt * 16 + l15, mt * 16 + l4 * 4 + r,
                 f2bf(o1[bb][dt][r]));
    }
    __syncthreads();

    // ---- S2 + P2A fused (B=Q, PV-B=avT) + dwconv + act store (fp32, once) ----
    f32x4 o2[2][4];
    fused(OFF_Q, OFF_K, 1, h, o2);
    if (mt < 11) {
#pragma unroll
      for (int dt = 0; dt < 4; ++dt) {
        const int d = dt * 16 + l15;
        const int c = h * 64 + d;
        const float bc = dwc_b[c];
#pragma unroll
        for (int r = 0; r < 4; ++r) {
          const int n = mt * 16 + l4 * 4 + r;
          const int nl = n > 168 ? 168 : n;
          const int y = (nl * 79) >> 10;
          const int xx = nl - y * 13;
          float dw0 = bc, dw1 = bc;
#pragma unroll
          for (int ky = 0; ky < 3; ++ky) {
            const int yy = y + ky - 1;
            if ((unsigned)yy >= 13u) continue;
#pragma unroll
            for (int kx = 0; kx < 3; ++kx) {
              const int x2 = xx + kx - 1;
              if ((unsigned)x2 >= 13u) continue;
              const float wv = dwc_w[c * 9 + ky * 3 + kx];   // shared table
              dw0 += wv * ld2p(sm, 0 * BSTR + OFF_V, 352, d, yy * 13 + x2);
              dw1 += wv * ld2p(sm, 1 * BSTR + OFF_V, 352, d, yy * 13 + x2);
            }
          }
          if (n < 169) {
            __builtin_nontemporal_store(o2[0][dt][r] + dw0, op[0] + (size_t)n * 256 + c);
            __builtin_nontemporal_store(o2[1][dt][r] + dw1, op[1] + (size_t)n * 256 + c);
          }
        }
      }
    }
    // next head's loop-top barrier protects Q/K/V regions (dwconv reads done)
  }
}

// ---------------- proj GEMM: in-place out = act @ proj_w^T + proj_b ----------------
__global__ __launch_bounds__(512, 1) void proj_kernel(
    const float* __restrict__ pwf, const float* __restrict__ pb,
    float* __restrict__ out)
{
  __shared__ __align__(16) char sm[30720];   // As[128][80B] = 10240, Bs[256][80B] = 20480
  const int bm = blockIdx.x;                 // 1352 row-blocks of 128
  const int tid = threadIdx.x;
  const int wave = tid >> 6;                 // 0..7
  const int lane = tid & 63;
  const int l15 = lane & 15;
  const int l4 = lane >> 4;
  const int wr = (wave >> 2) * 64;           // 0,64
  const int wc = (wave & 3) * 64;            // 0,64,128,192

  f32x4 acc[4][4];
  const f32x4 z = {0.f, 0.f, 0.f, 0.f};
#pragma unroll
  for (int i = 0; i < 4; ++i)
#pragma unroll
    for (int j = 0; j < 4; ++j) acc[i][j] = z;

  const int arow = tid >> 1, ahalf = tid & 1;        // A: threads 0..255
  const int brow = tid >> 1, bhalf = tid & 1;        // B: all threads
  const float* asrc = out + ((size_t)bm * 128 + arow) * 256 + ahalf * 16;
  const float* bsrc = pwf + (size_t)brow * 256 + bhalf * 16;

  for (int kit = 0; kit < 8; ++kit) {
    const int k0 = kit * 32;
    bf16x8 aA0, aA1, aB0, aB1;
    if (tid < 256) {
      float4 f0 = *(const float4*)(asrc + k0);
      float4 f1 = *(const float4*)(asrc + k0 + 4);
      float4 f2 = *(const float4*)(asrc + k0 + 8);
      float4 f3 = *(const float4*)(asrc + k0 + 12);
      aA0 = cvt8(f0, f1); aA1 = cvt8(f2, f3);
    }
    {
      float4 f0 = *(const float4*)(bsrc + k0);
      float4 f1 = *(const float4*)(bsrc + k0 + 4);
      float4 f2 = *(const float4*)(bsrc + k0 + 8);
      float4 f3 = *(const float4*)(bsrc + k0 + 12);
      aB0 = cvt8(f0, f1); aB1 = cvt8(f2, f3);
    }
    __syncthreads();
    if (tid < 256) {
      *(bf16x8*)(sm + arow * 80 + ahalf * 32) = aA0;
      *(bf16x8*)(sm + arow * 80 + ahalf * 32 + 16) = aA1;
    }
    *(bf16x8*)(sm + 10240 + brow * 80 + bhalf * 32) = aB0;
    *(bf16x8*)(sm + 10240 + brow * 80 + bhalf * 32 + 16) = aB1;
    __syncthreads();
    bf16x8 afr[4], bfr[4];
#pragma unroll
    for (int mt = 0; mt < 4; ++mt)
      afr[mt] = *(const bf16x8*)(sm + (wr + mt * 16 + l15) * 80 + l4 * 16);
#pragma unroll
    for (int nt = 0; nt < 4; ++nt)
      bfr[nt] = *(const bf16x8*)(sm + 10240 + (wc + nt * 16 + l15) * 80 + l4 * 16);
#pragma unroll
    for (int mt = 0; mt < 4; ++mt)
#pragma unroll
      for (int nt = 0; nt < 4; ++nt)
        acc[mt][nt] = mfma16(afr[mt], bfr[nt], acc[mt][nt]);
  }
#pragma unroll
  for (int nt = 0; nt < 4; ++nt) {
    const int gcol = wc + nt * 16 + l15;
    const float bias = pb[gcol];
#pragma unroll
    for (int mt = 0; mt < 4; ++mt)
#pragma unroll
      for (int r = 0; r < 4; ++r) {
        const size_t grow = (size_t)bm * 128 + wr + mt * 16 + l4 * 4 + r;
        out[grow * 256 + gcol] = acc[mt][nt][r] + bias;
      }
  }
}

extern "C" void kernel_launch(void* const* d_in, const int* in_sizes, int n_in,
                              void* d_out, int out_size, void* d_ws, size_t ws_size,
                              hipStream_t stream) {
  const float* x      = (const float*)d_in[0];
  const float* qkv_w  = (const float*)d_in[1];
  const float* proj_w = (const float*)d_in[2];
  const float* proj_b = (const float*)d_in[3];
  const float* dwc_w  = (const float*)d_in[4];
  const float* dwc_b  = (const float*)d_in[5];
  const float* an     = (const float*)d_in[6];
  const float* na     = (const float*)d_in[7];
  const float* ah     = (const float*)d_in[8];
  const float* aw     = (const float*)d_in[9];
  const float* ha     = (const float*)d_in[10];
  const float* wa     = (const float*)d_in[11];
  float* outp = (float*)d_out;

  attn_kernel<<<512, 768, 0, stream>>>(
      x, qkv_w, dwc_w, dwc_b, an, ah, aw, na, ha, wa, outp);
  proj_kernel<<<1352, 512, 0, stream>>>(proj_w, proj_b, outp);
}

// Round 20
// 1064.276 us; speedup vs baseline: 2.4568x; 1.4592x over previous
//
#include <hip/hip_runtime.h>

// Round 20: round 19 (green) + prep kernel into SMALL guarded workspace:
//  - pos1[h][a][n], abias[h][n][a]: 3-term biases prefolded (914KB fp32)
//  - qkvb: qkv_w pre-converted bf16 (393KB)
//  Total 1.31MB, gated on ws_size >= 1307168 with a compiled USEWS=0 fallback
//  (= exact round-19 path). Hot kernel: bias = 1 load (was 3), QKV weight =
//  1 bf16x8 load (was 2 float4 + 16-op cvt chain). All else unchanged.

typedef __attribute__((ext_vector_type(8))) short bf16x8;
typedef __attribute__((ext_vector_type(4))) float f32x4;

#define BSTR  67584      // per-b region: Q[0,22528) K/avT[22528,45056) V[45056,67584)
#define OFF_Q 0
#define OFF_K 22528
#define OFF_V 45056
#define OFF_T 135168     // P_tmp: per (wave,bb) 1152B = [16][36 bf16] stride 72
#define SMEM_BYTES 162816
#define WS_NEED 1307168ull

__device__ __forceinline__ unsigned short f2bf(float f) {
  unsigned int u = __float_as_uint(f);
  u += 0x7FFFu + ((u >> 16) & 1u);
  return (unsigned short)(u >> 16);
}
__device__ __forceinline__ float bf2f(unsigned short v) {
  return __uint_as_float(((unsigned int)v) << 16);
}
__device__ __forceinline__ f32x4 mfma16(bf16x8 a, bf16x8 b, f32x4 c) {
  return __builtin_amdgcn_mfma_f32_16x16x32_bf16(a, b, c, 0, 0, 0);
}
__device__ __forceinline__ bf16x8 cvt8(float4 a, float4 b) {
  bf16x8 v;
  v[0] = (short)f2bf(a.x); v[1] = (short)f2bf(a.y);
  v[2] = (short)f2bf(a.z); v[3] = (short)f2bf(a.w);
  v[4] = (short)f2bf(b.x); v[5] = (short)f2bf(b.y);
  v[6] = (short)f2bf(b.z); v[7] = (short)f2bf(b.w);
  return v;
}
// swizzled (stride multiple of 128; base multiple of 128)
__device__ __forceinline__ bf16x8 ld8s(const char* sm, int base, int stride, int row, int colbyte) {
  return *(const bf16x8*)(sm + base + row * stride + (colbyte ^ ((row & 7) << 4)));
}
__device__ __forceinline__ void st2s(char* sm, int base, int stride, int row, int col, unsigned short v) {
  *(unsigned short*)(sm + base + row * stride + ((col * 2) ^ ((row & 7) << 4))) = v;
}
// plain (any stride)
__device__ __forceinline__ bf16x8 ld8p(const char* sm, int base, int stride, int row, int colbyte) {
  return *(const bf16x8*)(sm + base + row * stride + colbyte);
}
__device__ __forceinline__ void st2p(char* sm, int base, int stride, int row, int col, unsigned short v) {
  *(unsigned short*)(sm + base + row * stride + col * 2) = v;
}
__device__ __forceinline__ float ld2p(const char* sm, int base, int stride, int row, int col) {
  return bf2f(*(const unsigned short*)(sm + base + row * stride + col * 2));
}

// ---------------- prep: fold biases + bf16 qkv_w ----------------
__global__ void prep_kernel(
    const float* __restrict__ qkv_w,
    const float* __restrict__ an, const float* __restrict__ ah,
    const float* __restrict__ aw, const float* __restrict__ na,
    const float* __restrict__ ha, const float* __restrict__ wa,
    float* __restrict__ pos1, float* __restrict__ abias,
    unsigned short* __restrict__ qkvb)
{
  const int i = blockIdx.x * 256 + threadIdx.x;
  if (i < 114244) {                       // pos1[h][a][n]
    const int hh = i / 28561;
    const int rem = i - hh * 28561;
    const int a = rem / 169;
    const int n = rem - a * 169;
    const int y = n / 13;
    const int xx = n - y * 13;
    pos1[i] = an[i] + ah[(hh * 169 + a) * 13 + y] + aw[(hh * 169 + a) * 13 + xx];
  } else if (i < 228488) {                // abias[h][n][a]
    const int j = i - 114244;
    const int hh = j / 28561;
    const int rem = j - hh * 28561;
    const int n = rem / 169;
    const int a = rem - n * 169;
    const int y = n / 13;
    const int xx = n - y * 13;
    abias[j] = na[(hh * 169 + a) * 169 + n] + ha[(hh * 13 + y) * 169 + a]
             + wa[(hh * 13 + xx) * 169 + a];
  } else if (i < 425096) {                // qkv_w -> bf16 (196608 elems)
    const int k = i - 228488;
    qkvb[k] = f2bf(qkv_w[k]);
  }
}

template<int USEWS>
__global__ __launch_bounds__(768) void attn_kernel(
    const float* __restrict__ x, const float* __restrict__ qkv_w,
    const float* __restrict__ dwc_w, const float* __restrict__ dwc_b,
    const float* __restrict__ an, const float* __restrict__ ah,
    const float* __restrict__ aw, const float* __restrict__ na,
    const float* __restrict__ ha, const float* __restrict__ wa,
    const float* __restrict__ pos1, const float* __restrict__ abias,
    const unsigned short* __restrict__ qkvb,
    float* __restrict__ out)
{
  __shared__ __align__(16) char sm[SMEM_BYTES];
  const int tid = threadIdx.x;
  const int wave = tid >> 6;        // 0..11; mt = wave; wave 11 idle in compute
  const int lane = tid & 63;
  const int l15 = lane & 15;
  const int l4 = lane >> 4;
  const int mt = wave;
  const f32x4 z = {0.f, 0.f, 0.f, 0.f};

  const float* xbp[2];
  float* op[2];
  xbp[0] = x + (size_t)blockIdx.x * 43264;            // 169*256
  xbp[1] = x + (size_t)(blockIdx.x + 512) * 43264;
  op[0] = out + (size_t)blockIdx.x * 43264;
  op[1] = out + (size_t)(blockIdx.x + 512) * 43264;

  // one-time LDS zero: stray bytes must never decode to Inf/NaN
  {
    int* p = (int*)sm;
    for (int i = tid; i < SMEM_BYTES / 4; i += 768) p[i] = 0;
  }

  // fused S-phase (in-reg softmax, shared bias) + PV via per-(wave,bb) P_tmp.
  auto fused = [&](int sOff, int pvOff, int which, int h, f32x4 (&o)[2][4]) {
#pragma unroll
    for (int bb = 0; bb < 2; ++bb)
#pragma unroll
      for (int dt = 0; dt < 4; ++dt) o[bb][dt] = z;
    if (mt >= 11) return;
    const int arow = mt * 16 + l15;
    const int rbase = mt * 16 + l4 * 4;
    bf16x8 a0[2], a1[2];
#pragma unroll
    for (int bb = 0; bb < 2; ++bb) {
      a0[bb] = ld8s(sm, bb * BSTR + OFF_Q, 128, arow, l4 * 16);
      a1[bb] = ld8s(sm, bb * BSTR + OFF_Q, 128, arow, 64 + l4 * 16);
    }
    f32x4 s[2][11];
#pragma unroll
    for (int nt = 0; nt < 11; ++nt) {
      const int brow = nt * 16 + l15;
#pragma unroll
      for (int bb = 0; bb < 2; ++bb) {
        bf16x8 b0 = ld8s(sm, bb * BSTR + sOff, 128, brow, l4 * 16);
        bf16x8 b1 = ld8s(sm, bb * BSTR + sOff, 128, brow, 64 + l4 * 16);
        f32x4 c = z;
        c = mfma16(a0[bb], b0, c);
        c = mfma16(a1[bb], b1, c);
        s[bb][nt] = c;
      }
    }
    // bias (SHARED between the two b's) + mask
    const float* bt = (which == 0) ? (pos1 + h * 28561) : (abias + h * 28561);
#pragma unroll
    for (int nt = 0; nt < 11; ++nt) {
      const int cc = nt * 16 + l15;
      const int ccl = cc > 168 ? 168 : cc;
      const int yc = (ccl * 79) >> 10;
      const int xc = ccl - yc * 13;
#pragma unroll
      for (int r = 0; r < 4; ++r) {
        const int rr = rbase + r;
        const int rrl = rr > 168 ? 168 : rr;
        float bias;
        if constexpr (USEWS) {
          bias = bt[rrl * 169 + ccl];
        } else {
          if (which == 0) {
            bias = an[h * 28561 + rrl * 169 + ccl]
                 + ah[(h * 169 + rrl) * 13 + yc]
                 + aw[(h * 169 + rrl) * 13 + xc];
          } else {
            const int yn = (rrl * 79) >> 10;
            const int xn = rrl - yn * 13;
            bias = na[h * 28561 + ccl * 169 + rrl]
                 + ha[(h * 13 + yn) * 169 + ccl]
                 + wa[(h * 13 + xn) * 169 + ccl];
          }
        }
#pragma unroll
        for (int bb = 0; bb < 2; ++bb) {
          const float v = s[bb][nt][r] * 0.125f + bias;
          s[bb][nt][r] = (cc > 168) ? -3.0e38f : v;
        }
      }
    }
    // in-register softmax (two independent chains)
#pragma unroll
    for (int bb = 0; bb < 2; ++bb)
#pragma unroll
      for (int r = 0; r < 4; ++r) {
        float m = s[bb][0][r];
#pragma unroll
        for (int nt = 1; nt < 11; ++nt) m = fmaxf(m, s[bb][nt][r]);
        m = fmaxf(m, __shfl_xor(m, 1));
        m = fmaxf(m, __shfl_xor(m, 2));
        m = fmaxf(m, __shfl_xor(m, 4));
        m = fmaxf(m, __shfl_xor(m, 8));
        float sum = 0.f;
#pragma unroll
        for (int nt = 0; nt < 11; ++nt) { const float e = __expf(s[bb][nt][r] - m); s[bb][nt][r] = e; sum += e; }
        sum += __shfl_xor(sum, 1);
        sum += __shfl_xor(sum, 2);
        sum += __shfl_xor(sum, 4);
        sum += __shfl_xor(sum, 8);
        const float inv = 1.f / sum;
#pragma unroll
        for (int nt = 0; nt < 11; ++nt) s[bb][nt][r] *= inv;
      }
    // PV: per 32-wide chunk pair, through per-(wave,bb) P_tmp
#pragma unroll
    for (int np = 0; np < 6; ++np) {
      const int nt1 = 2 * np + 1;
      bf16x8 af[2];
#pragma unroll
      for (int bb = 0; bb < 2; ++bb) {
        const int tb = OFF_T + (wave * 2 + bb) * 1152;
#pragma unroll
        for (int r = 0; r < 4; ++r) {
          char* prow = sm + tb + (l4 * 4 + r) * 72;
          *(unsigned short*)(prow + l15 * 2) = f2bf(s[bb][2 * np][r]);
          *(unsigned short*)(prow + 32 + l15 * 2) =
              (nt1 < 11) ? f2bf(s[bb][nt1][r]) : (unsigned short)0;
        }
        af[bb] = *(const bf16x8*)(sm + tb + l15 * 72 + l4 * 16);
      }
#pragma unroll
      for (int dt = 0; dt < 4; ++dt)
#pragma unroll
        for (int bb = 0; bb < 2; ++bb) {
          bf16x8 bv = ld8p(sm, bb * BSTR + pvOff, 352, dt * 16 + l15, np * 64 + l4 * 16);
          o[bb][dt] = mfma16(af[bb], bv, o[bb][dt]);
        }
    }
  };

  for (int h = 0; h < 4; ++h) {
    __syncthreads();   // previous head fully consumed (and initial zero done)

    // ---- QKV: [176 x 192] = x[b] @ w_head^T; w-frags SHARED across b ----
    if (mt < 11) {
      f32x4 acc[2][12];
#pragma unroll
      for (int bb = 0; bb < 2; ++bb)
#pragma unroll
        for (int i = 0; i < 12; ++i) acc[bb][i] = z;
      const int arow = mt * 16 + l15;
      const int gr = arow < 169 ? arow : 168;

      for (int ks = 0; ks < 8; ++ks) {
        bf16x8 af[2];
#pragma unroll
        for (int bb = 0; bb < 2; ++bb) {
          const float* p0 = xbp[bb] + gr * 256 + ks * 32 + l4 * 8;
          af[bb] = cvt8(*(const float4*)p0, *(const float4*)(p0 + 4));  // cached
        }
#pragma unroll
        for (int nt = 0; nt < 12; ++nt) {
          const int wrow = nt * 16 + l15;
          const int grow = ((wrow >> 6) << 8) + h * 64 + (wrow & 63);
          bf16x8 bw;
          if constexpr (USEWS) {
            bw = *(const bf16x8*)(qkvb + (size_t)grow * 256 + ks * 32 + l4 * 8);
          } else {
            const float* wp = qkv_w + grow * 256 + ks * 32 + l4 * 8;
            bw = cvt8(*(const float4*)wp, *(const float4*)(wp + 4));
          }
          acc[0][nt] = mfma16(af[0], bw, acc[0][nt]);
          acc[1][nt] = mfma16(af[1], bw, acc[1][nt]);
        }
      }
      // write Q,K (stride 128, swz); V transposed [d][n] (stride 352, plain)
#pragma unroll
      for (int nt = 0; nt < 12; ++nt) {
        const int mat = nt >> 2;
        const int d = (nt & 3) * 16 + l15;
#pragma unroll
        for (int r = 0; r < 4; ++r) {
          const int n = mt * 16 + l4 * 4 + r;
#pragma unroll
          for (int bb = 0; bb < 2; ++bb) {
            const unsigned short u = f2bf(acc[bb][nt][r]);
            if (mat == 0)      st2s(sm, bb * BSTR + OFF_Q, 128, n, d, u);
            else if (mat == 1) st2s(sm, bb * BSTR + OFF_K, 128, n, d, u);
            else               st2p(sm, bb * BSTR + OFF_V, 352, d, n, u);
          }
        }
      }
    }
    __syncthreads();

    // ---- S1 + P1V fused (B=K, PV-B=Vt) -> agent_v rows in regs ----
    f32x4 o1[2][4];
    fused(OFF_K, OFF_V, 0, h, o1);
    __syncthreads();                 // all S1 reads of K done
    // write avT [d][a] over K region (stride 352, plain)
    if (mt < 11) {
#pragma unroll
      for (int bb = 0; bb < 2; ++bb)
#pragma unroll
        for (int dt = 0; dt < 4; ++dt)
#pragma unroll
          for (int r = 0; r < 4; ++r)
            st2p(sm, bb * BSTR + OFF_K, 352, dt * 16 + l15, mt * 16 + l4 * 4 + r,
                 f2bf(o1[bb][dt][r]));
    }
    __syncthreads();

    // ---- S2 + P2A fused (B=Q, PV-B=avT) + dwconv + act store (fp32, once) ----
    f32x4 o2[2][4];
    fused(OFF_Q, OFF_K, 1, h, o2);
    if (mt < 11) {
#pragma unroll
      for (int dt = 0; dt < 4; ++dt) {
        const int d = dt * 16 + l15;
        const int c = h * 64 + d;
        const float bc = dwc_b[c];
#pragma unroll
        for (int r = 0; r < 4; ++r) {
          const int n = mt * 16 + l4 * 4 + r;
          const int nl = n > 168 ? 168 : n;
          const int y = (nl * 79) >> 10;
          const int xx = nl - y * 13;
          float dw0 = bc, dw1 = bc;
#pragma unroll
          for (int ky = 0; ky < 3; ++ky) {
            const int yy = y + ky - 1;
            if ((unsigned)yy >= 13u) continue;
#pragma unroll
            for (int kx = 0; kx < 3; ++kx) {
              const int x2 = xx + kx - 1;
              if ((unsigned)x2 >= 13u) continue;
              const float wv = dwc_w[c * 9 + ky * 3 + kx];   // shared table
              dw0 += wv * ld2p(sm, 0 * BSTR + OFF_V, 352, d, yy * 13 + x2);
              dw1 += wv * ld2p(sm, 1 * BSTR + OFF_V, 352, d, yy * 13 + x2);
            }
          }
          if (n < 169) {
            __builtin_nontemporal_store(o2[0][dt][r] + dw0, op[0] + (size_t)n * 256 + c);
            __builtin_nontemporal_store(o2[1][dt][r] + dw1, op[1] + (size_t)n * 256 + c);
          }
        }
      }
    }
    // next head's loop-top barrier protects Q/K/V regions (dwconv reads done)
  }
}

// ---------------- proj GEMM: in-place out = act @ proj_w^T + proj_b ----------------
__global__ __launch_bounds__(512, 1) void proj_kernel(
    const float* __restrict__ pwf, const float* __restrict__ pb,
    float* __restrict__ out)
{
  __shared__ __align__(16) char sm[30720];   // As[128][80B] = 10240, Bs[256][80B] = 20480
  const int bm = blockIdx.x;                 // 1352 row-blocks of 128
  const int tid = threadIdx.x;
  const int wave = tid >> 6;                 // 0..7
  const int lane = tid & 63;
  const int l15 = lane & 15;
  const int l4 = lane >> 4;
  const int wr = (wave >> 2) * 64;           // 0,64
  const int wc = (wave & 3) * 64;            // 0,64,128,192

  f32x4 acc[4][4];
  const f32x4 z = {0.f, 0.f, 0.f, 0.f};
#pragma unroll
  for (int i = 0; i < 4; ++i)
#pragma unroll
    for (int j = 0; j < 4; ++j) acc[i][j] = z;

  const int arow = tid >> 1, ahalf = tid & 1;        // A: threads 0..255
  const int brow = tid >> 1, bhalf = tid & 1;        // B: all threads
  const float* asrc = out + ((size_t)bm * 128 + arow) * 256 + ahalf * 16;
  const float* bsrc = pwf + (size_t)brow * 256 + bhalf * 16;

  for (int kit = 0; kit < 8; ++kit) {
    const int k0 = kit * 32;
    bf16x8 aA0, aA1, aB0, aB1;
    if (tid < 256) {
      float4 f0 = *(const float4*)(asrc + k0);
      float4 f1 = *(const float4*)(asrc + k0 + 4);
      float4 f2 = *(const float4*)(asrc + k0 + 8);
      float4 f3 = *(const float4*)(asrc + k0 + 12);
      aA0 = cvt8(f0, f1); aA1 = cvt8(f2, f3);
    }
    {
      float4 f0 = *(const float4*)(bsrc + k0);
      float4 f1 = *(const float4*)(bsrc + k0 + 4);
      float4 f2 = *(const float4*)(bsrc + k0 + 8);
      float4 f3 = *(const float4*)(bsrc + k0 + 12);
      aB0 = cvt8(f0, f1); aB1 = cvt8(f2, f3);
    }
    __syncthreads();
    if (tid < 256) {
      *(bf16x8*)(sm + arow * 80 + ahalf * 32) = aA0;
      *(bf16x8*)(sm + arow * 80 + ahalf * 32 + 16) = aA1;
    }
    *(bf16x8*)(sm + 10240 + brow * 80 + bhalf * 32) = aB0;
    *(bf16x8*)(sm + 10240 + brow * 80 + bhalf * 32 + 16) = aB1;
    __syncthreads();
    bf16x8 afr[4], bfr[4];
#pragma unroll
    for (int mt = 0; mt < 4; ++mt)
      afr[mt] = *(const bf16x8*)(sm + (wr + mt * 16 + l15) * 80 + l4 * 16);
#pragma unroll
    for (int nt = 0; nt < 4; ++nt)
      bfr[nt] = *(const bf16x8*)(sm + 10240 + (wc + nt * 16 + l15) * 80 + l4 * 16);
#pragma unroll
    for (int mt = 0; mt < 4; ++mt)
#pragma unroll
      for (int nt = 0; nt < 4; ++nt)
        acc[mt][nt] = mfma16(afr[mt], bfr[nt], acc[mt][nt]);
  }
#pragma unroll
  for (int nt = 0; nt < 4; ++nt) {
    const int gcol = wc + nt * 16 + l15;
    const float bias = pb[gcol];
#pragma unroll
    for (int mt = 0; mt < 4; ++mt)
#pragma unroll
      for (int r = 0; r < 4; ++r) {
        const size_t grow = (size_t)bm * 128 + wr + mt * 16 + l4 * 4 + r;
        out[grow * 256 + gcol] = acc[mt][nt][r] + bias;
      }
  }
}

extern "C" void kernel_launch(void* const* d_in, const int* in_sizes, int n_in,
                              void* d_out, int out_size, void* d_ws, size_t ws_size,
                              hipStream_t stream) {
  const float* x      = (const float*)d_in[0];
  const float* qkv_w  = (const float*)d_in[1];
  const float* proj_w = (const float*)d_in[2];
  const float* proj_b = (const float*)d_in[3];
  const float* dwc_w  = (const float*)d_in[4];
  const float* dwc_b  = (const float*)d_in[5];
  const float* an     = (const float*)d_in[6];
  const float* na     = (const float*)d_in[7];
  const float* ah     = (const float*)d_in[8];
  const float* aw     = (const float*)d_in[9];
  const float* ha     = (const float*)d_in[10];
  const float* wa     = (const float*)d_in[11];
  float* outp = (float*)d_out;

  const bool usews = (d_ws != nullptr) && (ws_size >= WS_NEED);
  if (usews) {
    char* ws = (char*)d_ws;
    float* pos1  = (float*)ws;                         // 456,976 B
    float* abias = (float*)(ws + 456976);              // 456,976 B
    unsigned short* qkvb = (unsigned short*)(ws + 913952);  // 393,216 B
    prep_kernel<<<1661, 256, 0, stream>>>(qkv_w, an, ah, aw, na, ha, wa,
                                          pos1, abias, qkvb);
    attn_kernel<1><<<512, 768, 0, stream>>>(
        x, qkv_w, dwc_w, dwc_b, an, ah, aw, na, ha, wa,
        pos1, abias, qkvb, outp);
  } else {
    attn_kernel<0><<<512, 768, 0, stream>>>(
        x, qkv_w, dwc_w, dwc_b, an, ah, aw, na, ha, wa,
        nullptr, nullptr, nullptr, outp);
  }
  proj_kernel<<<1352, 512, 0, stream>>>(proj_w, proj_b, outp);
}